// Round 13
// baseline (254.993 us; speedup 1.0000x reference)
//
#include <hip/hip_runtime.h>
#include <math.h>

#define BB 8
#define NN 2048
#define FIN 128
#define FOUT 64
#define TI 16
#define TJ 512
#define TJP (TJ + 8)      // +8 bf16 = 16B row pad: A-frag ds_read_b128 bank skew
#define NTILE (NN / TJ)   // 4 j-tiles, one per block (R11 j-split)

typedef short bf16x8 __attribute__((ext_vector_type(8)));
typedef float f32x4 __attribute__((ext_vector_type(4)));

// exp(tanh(z)) = exp((u-1)/(u+1)), u = e^{2z}; v_rcp instead of precise div.
__device__ __forceinline__ float exp_tanh(float z) {
    float zc = fminf(fmaxf(z, -15.f), 15.f);
    float u = __expf(zc + zc);
    float tn = (u - 1.f) * __builtin_amdgcn_rcpf(u + 1.f);
    return __expf(tn);
}

__device__ __forceinline__ unsigned short f2bf(float x) {
    union { float f; unsigned u; } v; v.f = x;
    unsigned r = v.u + 0x7FFF + ((v.u >> 16) & 1);   // round-to-nearest-even
    return (unsigned short)(r >> 16);
}

// PACK: adj -> bitmask, STANDALONE zero-LDS kernel (R12 fused it into k01
// whose 40 KB static LDS capped the streaming pass at 2 blocks/CU — the
// likely cause of R12's 233->250 regression). 128 B/thread contiguous.
__global__ __launch_bounds__(256) void gat_pack(const int* __restrict__ adj,
                                                unsigned* __restrict__ pm) {
    size_t g = (size_t)blockIdx.x * 256 + threadIdx.x;   // word index
    const int4* src = (const int4*)(adj + (g << 5));
    unsigned m = 0;
#pragma unroll
    for (int q = 0; q < 8; ++q) {
        int4 v = src[q];
        m |= (v.x > 0 ? 1u : 0u) << (4 * q);
        m |= (v.y > 0 ? 2u : 0u) << (4 * q);
        m |= (v.z > 0 ? 4u : 0u) << (4 * q);
        m |= (v.w > 0 ? 8u : 0u) << (4 * q);
    }
    pm[g] = m;
}

// K1: h = x @ W -> bf16 TRANSPOSED ht[b][c][n]; f1 = h.a1, f2 = h.a2.
__global__ __launch_bounds__(256, 2) void gat_k1(const float* __restrict__ x,
                                                 const float* __restrict__ W,
                                                 const float* __restrict__ a,
                                                 unsigned short* __restrict__ ht,
                                                 float* __restrict__ f1,
                                                 float* __restrict__ f2) {
    __shared__ __attribute__((aligned(16))) float Wl[FIN][FOUT];  // 32 KB
    __shared__ __attribute__((aligned(16))) float xs[16][FIN];    // 8 KB
    int t = threadIdx.x;

    const float4* W4 = (const float4*)W;
    float4* Wl4 = (float4*)&Wl[0][0];
#pragma unroll
    for (int kk = 0; kk < 8; ++kk) Wl4[t + 256 * kk] = W4[t + 256 * kk];

    size_t row0 = (size_t)blockIdx.x * 16;
    const float4* x4 = (const float4*)(x + row0 * FIN);
    float4* xs4 = (float4*)&xs[0][0];
#pragma unroll
    for (int kk = 0; kk < 2; ++kk) xs4[t + 256 * kk] = x4[t + 256 * kk];
    __syncthreads();

    int c = t & 63;
    int rq = t >> 6;
    float acc[4] = {0.f, 0.f, 0.f, 0.f};
#pragma unroll 8
    for (int k = 0; k < FIN; ++k) {
        float wv = Wl[k][c];
        acc[0] = fmaf(xs[rq][k], wv, acc[0]);
        acc[1] = fmaf(xs[rq + 4][k], wv, acc[1]);
        acc[2] = fmaf(xs[rq + 8][k], wv, acc[2]);
        acc[3] = fmaf(xs[rq + 12][k], wv, acc[3]);
    }
    float a1c = a[c], a2c = a[FOUT + c];
#pragma unroll
    for (int m = 0; m < 4; ++m) {
        size_t bn = row0 + rq + 4 * m;
        int b = (int)(bn >> 11);
        int n = (int)(bn & 2047);
        ht[((size_t)b * FOUT + c) * NN + n] = f2bf(acc[m]);
        float p1 = acc[m] * a1c;
        float p2 = acc[m] * a2c;
#pragma unroll
        for (int off = 32; off > 0; off >>= 1) {
            p1 += __shfl_down(p1, off, 64);
            p2 += __shfl_down(p2, off, 64);
        }
        if (c == 0) { f1[bn] = p1; f2[bn] = p2; }
    }
}

// K2: one j-tile per block (R11 j-split); adj via 32x-smaller bitmask;
// NO atomics — per-tile slices of accg/rsp via plain stores, k3 reduces.
// (256,4) is the ONLY good launch bound (R3/4/6/8 evidence).
__global__ __launch_bounds__(256, 4) void gat_k2(const unsigned* __restrict__ pm,
                                                 const unsigned short* __restrict__ ht,
                                                 const float* __restrict__ f1,
                                                 const float* __restrict__ f2,
                                                 float* __restrict__ accg,
                                                 float* __restrict__ rsp) {
    __shared__ __attribute__((aligned(16))) unsigned short pb[TI][TJP];  // 16.6 KB
    __shared__ __attribute__((aligned(16))) float f2s[TJ];               // 2 KB
    __shared__ float f1s[TI];

    int t = threadIdx.x;
    int i0 = blockIdx.x * TI;
    int jt = blockIdx.y;
    int j0 = jt * TJ;
    int b = blockIdx.z;

    int lane = t & 63;
    int w = t >> 6;         // wave id -> c-tile
    int mrow = lane & 15;   // MFMA m / n index
    int quad = lane >> 4;   // MFMA k-quad

    // p-phase mapping: thread handles j4 = t&127 (4 j's), rows r0+2kk
    int j4 = t & 127;
    int r0 = t >> 7;        // wave-uniform

    // mask loads (8 x 4B, 8 lanes share each word) — issue before staging
    const unsigned* pmb = pm + (((size_t)b * NN + i0) << 6) + (j0 >> 5) + (j4 >> 3);
    unsigned mreg[8];
#pragma unroll
    for (int kk = 0; kk < 8; ++kk)
        mreg[kk] = pmb[(size_t)(r0 + 2 * kk) << 6];

    // stage this tile's f2 slice + f1s
    ((float2*)f2s)[t] = ((const float2*)(f2 + (size_t)b * NN + j0))[t];
    if (t < TI) f1s[t] = f1[(size_t)b * NN + i0 + t];
    __syncthreads();

    float f1r[8];
#pragma unroll
    for (int kk = 0; kk < 8; ++kk) f1r[kk] = f1s[r0 + 2 * kk];

    // ---- p-phase: mask bits -> exp(tanh) -> bf16 into LDS ----
    float4 fv = ((const float4*)f2s)[j4];
    int sh = 4 * (j4 & 7);
    float ps[8];
#pragma unroll
    for (int kk = 0; kk < 8; ++kk) {
        unsigned nib = mreg[kk] >> sh;
        float f1i = f1r[kk];
        float4 p;
        p.x = (nib & 1u) ? exp_tanh(f1i + fv.x) : 0.f;
        p.y = (nib & 2u) ? exp_tanh(f1i + fv.y) : 0.f;
        p.z = (nib & 4u) ? exp_tanh(f1i + fv.z) : 0.f;
        p.w = (nib & 8u) ? exp_tanh(f1i + fv.w) : 0.f;
        ps[kk] = p.x + p.y + p.z + p.w;
        ushort4 pk;
        pk.x = f2bf(p.x); pk.y = f2bf(p.y);
        pk.z = f2bf(p.z); pk.w = f2bf(p.w);
        *(ushort4*)&pb[r0 + 2 * kk][4 * j4] = pk;
    }
    __syncthreads();

    // ---- PV on matrix pipe: 16 chunks of K=32 ----
    const unsigned short* hp =
        ht + ((size_t)b * FOUT + w * 16 + mrow) * NN + j0 + 8 * quad;
    const unsigned short* prow = &pb[mrow][8 * quad];
    f32x4 acc = {0.f, 0.f, 0.f, 0.f};
#pragma unroll 4
    for (int ch = 0; ch < TJ / 32; ++ch) {
        bf16x8 af = *(const bf16x8*)(prow + 32 * ch);
        bf16x8 bf = *(const bf16x8*)(hp + 32 * ch);
        acc = __builtin_amdgcn_mfma_f32_16x16x32_bf16(af, bf, acc, 0, 0, 0);
    }

    // ---- rowsum partials: in-wave reduce, plain store per (tile,slot,row) ----
#pragma unroll
    for (int kk = 0; kk < 8; ++kk) {
        float s = ps[kk];
#pragma unroll
        for (int off = 32; off > 0; off >>= 1) s += __shfl_down(s, off, 64);
        if (lane == 0)
            rsp[(size_t)(jt * 2 + (w & 1)) * (BB * NN) +
                (size_t)b * NN + i0 + r0 + 2 * kk] = s;
    }
    // ---- acc partials: per-tile slice, plain stores ----
    float* ap = accg + (((size_t)jt * BB + b) * NN + i0) * FOUT + w * 16 + mrow;
#pragma unroll
    for (int u = 0; u < 4; ++u)
        ap[(size_t)(quad * 4 + u) * FOUT] = acc[u];
}

// K3: out = elu( (sum_tiles accg) / (sum rsp) ), coalesced float4.
__global__ __launch_bounds__(256) void gat_k3(const float* __restrict__ accg,
                                              const float* __restrict__ rsp,
                                              float* __restrict__ out) {
    int g4 = blockIdx.x * 256 + threadIdx.x;   // out float4 index (131072)
    int row = g4 >> 4;                         // b*N+i
    float s = 0.f;
#pragma unroll
    for (int q = 0; q < 2 * NTILE; ++q) s += rsp[(size_t)q * (BB * NN) + row];
    float rinv = __builtin_amdgcn_rcpf(s);
    const float4* ag = (const float4*)accg;
    float4 v = ag[g4];
#pragma unroll
    for (int tl = 1; tl < NTILE; ++tl) {
        float4 u = ag[(size_t)tl * (BB * NN * FOUT / 4) + g4];
        v.x += u.x; v.y += u.y; v.z += u.z; v.w += u.w;
    }
    float4 o;
    float sx = v.x * rinv; o.x = (sx > 0.f) ? sx : expm1f(sx);
    float sy = v.y * rinv; o.y = (sy > 0.f) ? sy : expm1f(sy);
    float sz = v.z * rinv; o.z = (sz > 0.f) ? sz : expm1f(sz);
    float sw = v.w * rinv; o.w = (sw > 0.f) ? sw : expm1f(sw);
    ((float4*)out)[g4] = o;
}

extern "C" void kernel_launch(void* const* d_in, const int* in_sizes, int n_in,
                              void* d_out, int out_size, void* d_ws, size_t ws_size,
                              hipStream_t stream) {
    const float* x   = (const float*)d_in[0];   // [B,N,128]
    const int*   adj = (const int*)d_in[1];     // [B,N,N]
    const float* W   = (const float*)d_in[2];   // [128,64]
    const float* a   = (const float*)d_in[3];   // [128,1]
    float* out = (float*)d_out;                 // [B,N,64]

    unsigned short* ht = (unsigned short*)d_ws;           // 2.1 MB bf16 [B][64][N]
    float* f1   = (float*)(ht + (size_t)BB * FOUT * NN);  // B*N
    float* f2   = f1 + (size_t)BB * NN;                   // B*N
    unsigned* pm = (unsigned*)(f2 + (size_t)BB * NN);     // B*N*64 words, 4.2 MB
    float* accg = (float*)(pm + (size_t)BB * NN * (NN / 32));  // NTILE*B*N*64, 16.8 MB
    float* rsp  = accg + (size_t)NTILE * BB * NN * FOUT;  // 2*NTILE*B*N, 512 KB

    gat_pack<<<dim3(BB * NN * NN / 32 / 256), dim3(256), 0, stream>>>(adj, pm);
    gat_k1<<<dim3(BB * NN / 16), dim3(256), 0, stream>>>(x, W, a, ht, f1, f2);
    gat_k2<<<dim3(NN / TI, NTILE, BB), dim3(256), 0, stream>>>(
        pm, ht, f1, f2, accg, rsp);
    gat_k3<<<dim3(BB * NN * FOUT / 1024), dim3(256), 0, stream>>>(accg, rsp, out);
}

// Round 14
// 231.704 us; speedup vs baseline: 1.1005x; 1.1005x over previous
//
#include <hip/hip_runtime.h>
#include <math.h>

#define BB 8
#define NN 2048
#define FIN 128
#define FOUT 64
#define TI 16
#define TJ 512
#define TJP (TJ + 8)      // +8 bf16 = 16B row pad: A-frag ds_read_b128 bank skew
#define NTILE (NN / TJ)   // 4 j-tiles, one per block (j-split)

typedef short bf16x8 __attribute__((ext_vector_type(8)));
typedef float f32x4 __attribute__((ext_vector_type(4)));

// exp(tanh(z)) = exp((u-1)/(u+1)), u = e^{2z}; v_rcp instead of precise div.
__device__ __forceinline__ float exp_tanh(float z) {
    float zc = fminf(fmaxf(z, -15.f), 15.f);
    float u = __expf(zc + zc);
    float tn = (u - 1.f) * __builtin_amdgcn_rcpf(u + 1.f);
    return __expf(tn);
}

__device__ __forceinline__ unsigned short f2bf(float x) {
    union { float f; unsigned u; } v; v.f = x;
    unsigned r = v.u + 0x7FFF + ((v.u >> 16) & 1);   // round-to-nearest-even
    return (unsigned short)(r >> 16);
}

// K1: h = x @ W -> bf16 TRANSPOSED ht[b][c][n]; f1 = h.a1, f2 = h.a2.
__global__ __launch_bounds__(256, 2) void gat_k1(const float* __restrict__ x,
                                                 const float* __restrict__ W,
                                                 const float* __restrict__ a,
                                                 unsigned short* __restrict__ ht,
                                                 float* __restrict__ f1,
                                                 float* __restrict__ f2) {
    __shared__ __attribute__((aligned(16))) float Wl[FIN][FOUT];  // 32 KB
    __shared__ __attribute__((aligned(16))) float xs[16][FIN];    // 8 KB
    int t = threadIdx.x;

    const float4* W4 = (const float4*)W;
    float4* Wl4 = (float4*)&Wl[0][0];
#pragma unroll
    for (int kk = 0; kk < 8; ++kk) Wl4[t + 256 * kk] = W4[t + 256 * kk];

    size_t row0 = (size_t)blockIdx.x * 16;
    const float4* x4 = (const float4*)(x + row0 * FIN);
    float4* xs4 = (float4*)&xs[0][0];
#pragma unroll
    for (int kk = 0; kk < 2; ++kk) xs4[t + 256 * kk] = x4[t + 256 * kk];
    __syncthreads();

    int c = t & 63;
    int rq = t >> 6;
    float acc[4] = {0.f, 0.f, 0.f, 0.f};
#pragma unroll 8
    for (int k = 0; k < FIN; ++k) {
        float wv = Wl[k][c];
        acc[0] = fmaf(xs[rq][k], wv, acc[0]);
        acc[1] = fmaf(xs[rq + 4][k], wv, acc[1]);
        acc[2] = fmaf(xs[rq + 8][k], wv, acc[2]);
        acc[3] = fmaf(xs[rq + 12][k], wv, acc[3]);
    }
    float a1c = a[c], a2c = a[FOUT + c];
#pragma unroll
    for (int m = 0; m < 4; ++m) {
        size_t bn = row0 + rq + 4 * m;
        int b = (int)(bn >> 11);
        int n = (int)(bn & 2047);
        ht[((size_t)b * FOUT + c) * NN + n] = f2bf(acc[m]);
        float p1 = acc[m] * a1c;
        float p2 = acc[m] * a2c;
#pragma unroll
        for (int off = 32; off > 0; off >>= 1) {
            p1 += __shfl_down(p1, off, 64);
            p2 += __shfl_down(p2, off, 64);
        }
        if (c == 0) { f1[bn] = p1; f2[bn] = p2; }
    }
}

// K2: one j-tile per block (R11 structure, exact). R14 delta: NO min-waves
// launch bound. Theory: k2 is HBM-latency x in-flight bound — 16 waves/CU x
// 8x16B adj loads = 2 KB in flight / 900 cyc => ~1.3 TB/s, matching R10's
// measured FETCH/dur and R11's ~70 us. Body needs ~56-64 VGPR naturally
// (R10: 64 with a bigger body); at <=64 VGPR + 18.8 KB LDS -> 8 blocks/CU,
// doubling in-flight bytes. FORCING min-waves (256,5/6) is what broke
// R3/4/6/8 (spill or ILP squeeze) — plain (256) never forces.
__global__ __launch_bounds__(256) void gat_k2(const int* __restrict__ adj,
                                              const unsigned short* __restrict__ ht,
                                              const float* __restrict__ f1,
                                              const float* __restrict__ f2,
                                              float* __restrict__ accg,
                                              float* __restrict__ rs) {
    __shared__ __attribute__((aligned(16))) unsigned short pb[TI][TJP];  // 16.6 KB
    __shared__ __attribute__((aligned(16))) float f2s[TJ];               // 2 KB
    __shared__ float f1s[TI];

    int t = threadIdx.x;
    int i0 = blockIdx.x * TI;
    int j0 = blockIdx.y * TJ;
    int b = blockIdx.z;

    int lane = t & 63;
    int w = t >> 6;         // wave id -> c-tile
    int mrow = lane & 15;   // MFMA m / n index
    int quad = lane >> 4;   // MFMA k-quad

    // p-phase mapping: thread handles j4 = t&127 (float4 group), rows r0+2kk
    int j4 = t & 127;
    int r0 = t >> 7;        // wave-uniform

    // adj loads issue immediately (cover with f2s staging + barrier)
    const int* adjbase = adj + (((size_t)b * NN + i0) * NN) + j0 + 4 * j4;
    int4 avreg[8];
#pragma unroll
    for (int kk = 0; kk < 8; ++kk)
        avreg[kk] = *(const int4*)(adjbase + (size_t)(r0 + 2 * kk) * NN);

    // stage this tile's f2 slice (512 floats) + f1s
    ((float2*)f2s)[t] = ((const float2*)(f2 + (size_t)b * NN + j0))[t];
    if (t < TI) f1s[t] = f1[(size_t)b * NN + i0 + t];
    __syncthreads();

    float f1r[8];
#pragma unroll
    for (int kk = 0; kk < 8; ++kk) f1r[kk] = f1s[r0 + 2 * kk];

    // ---- p-phase: mask -> exp(tanh) -> bf16 into LDS ----
    float4 fv = ((const float4*)f2s)[j4];
    float ps[8];
#pragma unroll
    for (int kk = 0; kk < 8; ++kk) {
        int4 av = avreg[kk];
        float f1i = f1r[kk];
        float4 p;
        p.x = (av.x > 0) ? exp_tanh(f1i + fv.x) : 0.f;
        p.y = (av.y > 0) ? exp_tanh(f1i + fv.y) : 0.f;
        p.z = (av.z > 0) ? exp_tanh(f1i + fv.z) : 0.f;
        p.w = (av.w > 0) ? exp_tanh(f1i + fv.w) : 0.f;
        ps[kk] = p.x + p.y + p.z + p.w;
        ushort4 pk;
        pk.x = f2bf(p.x); pk.y = f2bf(p.y);
        pk.z = f2bf(p.z); pk.w = f2bf(p.w);
        *(ushort4*)&pb[r0 + 2 * kk][4 * j4] = pk;
    }
    __syncthreads();

    // ---- PV on matrix pipe: 16 chunks of K=32 ----
    const unsigned short* hp =
        ht + ((size_t)b * FOUT + w * 16 + mrow) * NN + j0 + 8 * quad;
    const unsigned short* prow = &pb[mrow][8 * quad];
    f32x4 acc = {0.f, 0.f, 0.f, 0.f};
#pragma unroll 4
    for (int ch = 0; ch < TJ / 32; ++ch) {
        bf16x8 af = *(const bf16x8*)(prow + 32 * ch);
        bf16x8 bf = *(const bf16x8*)(hp + 32 * ch);
        acc = __builtin_amdgcn_mfma_f32_16x16x32_bf16(af, bf, acc, 0, 0, 0);
    }

    // ---- rowsum partials: in-wave reduce then one atomic per (wave,row) ----
#pragma unroll
    for (int kk = 0; kk < 8; ++kk) {
        float s = ps[kk];
#pragma unroll
        for (int off = 32; off > 0; off >>= 1) s += __shfl_down(s, off, 64);
        if (lane == 0)
            atomicAdd(&rs[(size_t)b * NN + i0 + r0 + 2 * kk], s);
    }
    // ---- acc partials: D-frag (col=lane&15, row=quad*4+u) ----
    float* ap = accg + ((size_t)b * NN + i0) * FOUT + w * 16 + mrow;
#pragma unroll
    for (int u = 0; u < 4; ++u) {
        int row = quad * 4 + u;
        atomicAdd(&ap[(size_t)row * FOUT], acc[u]);
    }
}

// K3: out = elu(acc / rowsum), fully coalesced float4.
__global__ __launch_bounds__(256) void gat_k3(const float* __restrict__ accg,
                                              const float* __restrict__ rs,
                                              float* __restrict__ out) {
    int g4 = blockIdx.x * 256 + threadIdx.x;   // float4 index
    int row = g4 >> 4;                         // 16 float4s per 64-col row
    float rinv = __builtin_amdgcn_rcpf(rs[row]);
    float4 v = ((const float4*)accg)[g4];
    float4 o;
    float sx = v.x * rinv; o.x = (sx > 0.f) ? sx : expm1f(sx);
    float sy = v.y * rinv; o.y = (sy > 0.f) ? sy : expm1f(sy);
    float sz = v.z * rinv; o.z = (sz > 0.f) ? sz : expm1f(sz);
    float sw = v.w * rinv; o.w = (sw > 0.f) ? sw : expm1f(sw);
    ((float4*)out)[g4] = o;
}

extern "C" void kernel_launch(void* const* d_in, const int* in_sizes, int n_in,
                              void* d_out, int out_size, void* d_ws, size_t ws_size,
                              hipStream_t stream) {
    const float* x   = (const float*)d_in[0];   // [B,N,128]
    const int*   adj = (const int*)d_in[1];     // [B,N,N]
    const float* W   = (const float*)d_in[2];   // [128,64]
    const float* a   = (const float*)d_in[3];   // [128,1]
    float* out = (float*)d_out;                 // [B,N,64]

    unsigned short* ht = (unsigned short*)d_ws;          // [B][64][2048] bf16, 2.1 MB
    float* f1   = (float*)(ht + (size_t)BB * FOUT * NN); // B*N
    float* f2   = f1 + (size_t)BB * NN;                  // B*N
    float* accg = f2 + (size_t)BB * NN;                  // B*N*64, 4.2 MB
    float* rs   = accg + (size_t)BB * NN * FOUT;         // B*N, 64 KB
    // zero the atomic accumulators (accg + rs contiguous)
    hipMemsetAsync(accg, 0, ((size_t)BB * NN * FOUT + (size_t)BB * NN) * 4, stream);

    gat_k1<<<dim3(BB * NN / 16), dim3(256), 0, stream>>>(x, W, a, ht, f1, f2);
    gat_k2<<<dim3(NN / TI, NTILE, BB), dim3(256), 0, stream>>>(adj, ht, f1, f2, accg, rs);
    gat_k3<<<dim3(BB * NN * FOUT / 1024), dim3(256), 0, stream>>>(accg, rs, out);
}